// Round 4
// baseline (206.712 us; speedup 1.0000x reference)
//
#include <hip/hip_runtime.h>
#include <math.h>

#define C_SIZE 2048
#define D_DIM  1024
#define H_DIM  1024
#define B_SIZE 32
#define S_LEN  64
#define G_NUM  16
#define NBLK   512   // 2 blocks/CU needed; capacity >=4 -> all co-resident, safe barrier

// ---- manual grid barrier (one-shot counters, zeroed by hipMemsetAsync each call) ----
__device__ __forceinline__ void grid_barrier(unsigned* cnt, int tid) {
    __syncthreads();                       // drains vmcnt: block's stores are in L2
    if (tid == 0) {
        __hip_atomic_fetch_add(cnt, 1u, __ATOMIC_RELEASE, __HIP_MEMORY_SCOPE_AGENT);
        for (int i = 0; i < (1 << 22); ++i) {   // bounded: fail -> wrong answer, not hang
            if (__hip_atomic_load(cnt, __ATOMIC_ACQUIRE, __HIP_MEMORY_SCOPE_AGENT) >= NBLK)
                break;
            __builtin_amdgcn_s_sleep(2);
        }
    }
    __syncthreads();                       // blockmates proceed after tid0's acquire-inv
}

// ws float layout:
//   [0..63]    barrier counters (uints; [0],[16],[32]) -- memset 256 B each call
//   hp      @64       (32*1024)
//   scoresT @32832    (32*2048)   [b][c]
//   pm      @98368    (16*32)     [g][b]
//   pl      @98880    (16*32)
//   Mb      @99392    (32)
//   Lb      @99424    (32)
//   ctxws   @99456    (32*1024)   [b][d]
//   pacc    @132224   (16*32*1024) [g][b][d]
__global__ __launch_bounds__(256, 2) void mega_kernel(
    const float* __restrict__ hidden,
    const float* __restrict__ W,
    const float* __restrict__ cv,
    const unsigned char* __restrict__ mask,
    float* __restrict__ out_ctx,
    float* __restrict__ out_attn,
    float* __restrict__ ws)
{
    unsigned* bar0 = (unsigned*)ws;
    unsigned* bar1 = (unsigned*)ws + 16;
    unsigned* bar2 = (unsigned*)ws + 32;
    float* hp      = ws + 64;
    float* scoresT = ws + 32832;
    float* pm      = ws + 98368;
    float* pl      = ws + 98880;
    float* Mb      = ws + 99392;
    float* Lb      = ws + 99424;
    float* ctxws   = ws + 99456;
    float* pacc    = ws + 132224;

    const int bid  = blockIdx.x;
    const int tid  = threadIdx.x;
    const int lane = tid & 63;
    const int wave = tid >> 6;

    __shared__ float accs[4][D_DIM];   // 16 KiB (phase B)
    __shared__ float sm[4], sl[4];
    __shared__ float ssc[G_NUM];

    // ================= Phase A: hp[b][d] = hidden[b,:] . W[d,:] =================
    {
        const int dg = bid >> 5;          // 0..15
        const int b  = bid & 31;
        const float* hrow = hidden + b * H_DIM;
        float4 h4[4];
#pragma unroll
        for (int k = 0; k < 4; ++k) h4[k] = *(const float4*)(hrow + k * 256 + 4 * lane);

        const int d0 = dg * 64 + wave * 16;               // 16 rows per wave
        const float* wp = W + (size_t)d0 * H_DIM + 4 * lane;
        float4 wb[2][4];
#pragma unroll
        for (int k = 0; k < 4; ++k) wb[0][k] = *(const float4*)(wp + k * 256);

#pragma unroll
        for (int i = 0; i < 16; ++i) {
            if (i < 15) {
                const float* wn = wp + (size_t)(i + 1) * H_DIM;
#pragma unroll
                for (int k = 0; k < 4; ++k) wb[(i + 1) & 1][k] = *(const float4*)(wn + k * 256);
            }
            float s = 0.f;
#pragma unroll
            for (int k = 0; k < 4; ++k) {
                float4 w4 = wb[i & 1][k];
                s += w4.x * h4[k].x + w4.y * h4[k].y + w4.z * h4[k].z + w4.w * h4[k].w;
            }
            for (int off = 32; off > 0; off >>= 1) s += __shfl_xor(s, off);
            if (lane == 0) hp[b * D_DIM + d0 + i] = s;
        }
    }

    grid_barrier(bar0, tid);

    // ======== Phase B: fused scores + online-softmax partial accumulation ========
    {
        const int g = bid >> 5;           // 0..15
        const int b = bid & 31;

        const float* hpb = hp + b * D_DIM;
        float4 hp4[4];
#pragma unroll
        for (int k = 0; k < 4; ++k) hp4[k] = *(const float4*)(hpb + k * 256 + 4 * lane);

        float  m = -3.0e38f, l = 0.f;
        float4 acc[4];
#pragma unroll
        for (int k = 0; k < 4; ++k) acc[k] = make_float4(0.f, 0.f, 0.f, 0.f);

        const int    c0      = g * 128 + wave * 32;       // 32 c's per wave
        const size_t cstride = (size_t)B_SIZE * D_DIM;
        const float* p0      = cv + ((size_t)c0 * B_SIZE + b) * D_DIM + 4 * lane;

        float4 nxt[4];
#pragma unroll
        for (int k = 0; k < 4; ++k) nxt[k] = *(const float4*)(p0 + k * 256);

        for (int i = 0; i < 32; ++i) {
            float4 cvv[4];
#pragma unroll
            for (int k = 0; k < 4; ++k) cvv[k] = nxt[k];
            if (i < 31) {
                const float* pn = p0 + (size_t)(i + 1) * cstride;
#pragma unroll
                for (int k = 0; k < 4; ++k) nxt[k] = *(const float4*)(pn + k * 256);
            }
            float s = 0.f;
#pragma unroll
            for (int k = 0; k < 4; ++k) {
                s += cvv[k].x * hp4[k].x + cvv[k].y * hp4[k].y +
                     cvv[k].z * hp4[k].z + cvv[k].w * hp4[k].w;
            }
            for (int off = 32; off > 0; off >>= 1) s += __shfl_xor(s, off);

            int c = c0 + i;
            if (mask[c * B_SIZE + b]) s = -3.0e38f;
            if (lane == 0) scoresT[b * C_SIZE + c] = s;

            // online update; s is wave-uniform -> uniform branch
            if (s <= m) {
                float p = __expf(s - m);
                l += p;
#pragma unroll
                for (int k = 0; k < 4; ++k) {
                    acc[k].x += p * cvv[k].x;
                    acc[k].y += p * cvv[k].y;
                    acc[k].z += p * cvv[k].z;
                    acc[k].w += p * cvv[k].w;
                }
            } else {
                float scale = __expf(m - s);   // first real row: exp(-huge)=0 wipes junk
                l = l * scale + 1.f;
#pragma unroll
                for (int k = 0; k < 4; ++k) {
                    acc[k].x = acc[k].x * scale + cvv[k].x;
                    acc[k].y = acc[k].y * scale + cvv[k].y;
                    acc[k].z = acc[k].z * scale + cvv[k].z;
                    acc[k].w = acc[k].w * scale + cvv[k].w;
                }
                m = s;
            }
        }

        // combine the 4 waves' partials within the block
        if (lane == 0) { sm[wave] = m; sl[wave] = l; }
        __syncthreads();

        float mb = fmaxf(fmaxf(sm[0], sm[1]), fmaxf(sm[2], sm[3]));
        float myscale = __expf(m - mb);
#pragma unroll
        for (int k = 0; k < 4; ++k) {
            float4 v = acc[k];
            v.x *= myscale; v.y *= myscale; v.z *= myscale; v.w *= myscale;
            *(float4*)&accs[wave][k * 256 + 4 * lane] = v;
        }
        float lb = 0.f;
#pragma unroll
        for (int w = 0; w < 4; ++w) lb += sl[w] * __expf(sm[w] - mb);
        __syncthreads();

        float4 r = make_float4(0.f, 0.f, 0.f, 0.f);
#pragma unroll
        for (int w = 0; w < 4; ++w) {
            float4 v = *(const float4*)&accs[w][tid * 4];
            r.x += v.x; r.y += v.y; r.z += v.z; r.w += v.w;
        }
        *(float4*)(pacc + ((size_t)g * B_SIZE + b) * D_DIM + tid * 4) = r;
        if (tid == 0) { pm[g * B_SIZE + b] = mb; pl[g * B_SIZE + b] = lb; }
    }

    grid_barrier(bar1, tid);

    // ========= Phase C0: reduce group partials -> ctxws[b][d] (+ M/L) =========
    if ((bid & 3) == 0) {             // 128 spread blocks
        int k  = bid >> 2;            // 0..127
        int b  = k >> 2;
        int dq = k & 3;

        float mg = (lane < G_NUM) ? pm[lane * B_SIZE + b] : -3.0e38f;
        float M = mg;
        for (int off = 32; off > 0; off >>= 1) M = fmaxf(M, __shfl_xor(M, off));
        float lg = (lane < G_NUM) ? pl[lane * B_SIZE + b] * __expf(mg - M) : 0.f;
        float L = lg;
        for (int off = 32; off > 0; off >>= 1) L += __shfl_xor(L, off);

        if (wave == 0 && lane < G_NUM) ssc[lane] = __expf(mg - M);
        __syncthreads();

        float invL = 1.f / L;
        int d = dq * 256 + tid;
        float r = 0.f;
#pragma unroll
        for (int gi = 0; gi < G_NUM; ++gi)
            r += ssc[gi] * pacc[(size_t)(gi * B_SIZE + b) * D_DIM + d];
        ctxws[b * D_DIM + d] = r * invL;

        if ((k & 3) == 0 && tid == 0) { Mb[b] = M; Lb[b] = L; }
    }

    grid_barrier(bar2, tid);

    // ================= Phase C1: write outputs (4 ctx + 4 attn rows) =================
    {
#pragma unroll
        for (int j = 0; j < 4; ++j) {          // context rows
            int r = bid + j * NBLK;            // 0..2047 = s*32+b
            int b = r & 31;
            float4 v = *(const float4*)(ctxws + b * D_DIM + tid * 4);
            *(float4*)(out_ctx + (size_t)r * D_DIM + tid * 4) = v;
        }
#pragma unroll
        for (int j = 0; j < 4; ++j) {          // attention rows
            int r = bid + j * NBLK;
            int b = r & 31;
            float M    = Mb[b];
            float invL = 1.f / Lb[b];
            const float* srow = scoresT + b * C_SIZE;
            float4* orow = (float4*)(out_attn + (size_t)r * C_SIZE);
#pragma unroll
            for (int kk = 0; kk < 2; ++kk) {
                int c4 = tid + kk * 256;
                float4 sv = *(const float4*)(srow + c4 * 4);
                float4 av;
                av.x = __expf(sv.x - M) * invL;
                av.y = __expf(sv.y - M) * invL;
                av.z = __expf(sv.z - M) * invL;
                av.w = __expf(sv.w - M) * invL;
                orow[c4] = av;
            }
        }
    }
}

extern "C" void kernel_launch(void* const* d_in, const int* in_sizes, int n_in,
                              void* d_out, int out_size, void* d_ws, size_t ws_size,
                              hipStream_t stream) {
    // inputs: 0=seqlen(int,unused; S_LEN=64 static), 1=hidden[1,B,H] f32,
    //         2=contextvects[C,B,D] f32, 3=W[D,H] f32, 4=padding_mask[C,B] bool
    const float*         hidden = (const float*)d_in[1];
    const float*         cv     = (const float*)d_in[2];
    const float*         W      = (const float*)d_in[3];
    const unsigned char* mask   = (const unsigned char*)d_in[4];

    float* out_ctx  = (float*)d_out;                                  // [S,B,D]
    float* out_attn = (float*)d_out + (size_t)S_LEN * B_SIZE * D_DIM; // [S,B,C]
    float* wsp      = (float*)d_ws;

    // zero the 3 barrier counters every call (graph-capturable memset node)
    hipMemsetAsync(d_ws, 0, 256, stream);

    mega_kernel<<<dim3(NBLK), dim3(256), 0, stream>>>(hidden, W, cv, mask,
                                                      out_ctx, out_attn, wsp);
}

// Round 5
// 67.781 us; speedup vs baseline: 3.0497x; 3.0497x over previous
//
#include <hip/hip_runtime.h>
#include <math.h>

#define C_SIZE 2048
#define D_DIM  1024
#define H_DIM  1024
#define B_SIZE 32
#define S_LEN  64
#define G_NUM  32               // c-groups in fused pass
#define CG     (C_SIZE / G_NUM) // 64 c per block, 16 per wave

// ---------------- Kernel 1: hidden_proj[b][d] = sum_h hidden[b][h] * W[d][h]
// grid = (B_SIZE, 32): 1024 blocks, 32 d-rows per block, 8 per wave.
__global__ __launch_bounds__(256) void hp_kernel(const float* __restrict__ hidden,
                                                 const float* __restrict__ W,
                                                 float* __restrict__ hp) {
    int b    = blockIdx.x;             // 0..31
    int dg   = blockIdx.y;             // 0..31
    int lane = threadIdx.x & 63;
    int wave = threadIdx.x >> 6;       // 0..3

    const float* hrow = hidden + b * H_DIM;
    float4 h4[4];
#pragma unroll
    for (int k = 0; k < 4; ++k) h4[k] = *(const float4*)(hrow + k * 256 + 4 * lane);

    const int d0 = dg * 32 + wave * 8;                 // 8 rows per wave
    const float* wp = W + (size_t)d0 * H_DIM + 4 * lane;
    float4 wb[2][4];
#pragma unroll
    for (int k = 0; k < 4; ++k) wb[0][k] = *(const float4*)(wp + k * 256);

#pragma unroll
    for (int i = 0; i < 8; ++i) {
        if (i < 7) {
            const float* wn = wp + (size_t)(i + 1) * H_DIM;
#pragma unroll
            for (int k = 0; k < 4; ++k) wb[(i + 1) & 1][k] = *(const float4*)(wn + k * 256);
        }
        float s = 0.f;
#pragma unroll
        for (int k = 0; k < 4; ++k) {
            float4 w4 = wb[i & 1][k];
            s += w4.x * h4[k].x + w4.y * h4[k].y + w4.z * h4[k].z + w4.w * h4[k].w;
        }
        for (int off = 32; off > 0; off >>= 1) s += __shfl_xor(s, off);
        if (lane == 0) hp[b * D_DIM + d0 + i] = s;
    }
}

// ---------------- Kernel 2: fused scores + online-softmax partial ctx accumulation
// grid = (G_NUM, B_SIZE), block = 256 (4 waves). Wave w handles 16 consecutive c's.
__global__ __launch_bounds__(256) void fused_kernel(const float* __restrict__ cv,
                                                    const float* __restrict__ hp,
                                                    const unsigned char* __restrict__ mask,
                                                    float* __restrict__ scoresT,
                                                    float* __restrict__ pm,
                                                    float* __restrict__ pl,
                                                    float* __restrict__ pacc) {
    int g    = blockIdx.x;
    int b    = blockIdx.y;
    int lane = threadIdx.x & 63;
    int wave = threadIdx.x >> 6;

    const float* hpb = hp + b * D_DIM;
    float4 hp4[4];
#pragma unroll
    for (int k = 0; k < 4; ++k) hp4[k] = *(const float4*)(hpb + k * 256 + 4 * lane);

    float  m = -3.0e38f, l = 0.f;
    float4 acc[4];
#pragma unroll
    for (int k = 0; k < 4; ++k) acc[k] = make_float4(0.f, 0.f, 0.f, 0.f);

    const int    c0      = g * CG + wave * (CG / 4);   // 16 c's for this wave
    const size_t cstride = (size_t)B_SIZE * D_DIM;
    const float* p0      = cv + ((size_t)c0 * B_SIZE + b) * D_DIM + 4 * lane;

    float4 nxt[4];
#pragma unroll
    for (int k = 0; k < 4; ++k) nxt[k] = *(const float4*)(p0 + k * 256);

    for (int i = 0; i < 16; ++i) {
        float4 cvv[4];
#pragma unroll
        for (int k = 0; k < 4; ++k) cvv[k] = nxt[k];
        if (i < 15) {
            const float* pn = p0 + (size_t)(i + 1) * cstride;
#pragma unroll
            for (int k = 0; k < 4; ++k) nxt[k] = *(const float4*)(pn + k * 256);
        }
        // dot(cv_row, hp_row)
        float s = 0.f;
#pragma unroll
        for (int k = 0; k < 4; ++k) {
            s += cvv[k].x * hp4[k].x + cvv[k].y * hp4[k].y +
                 cvv[k].z * hp4[k].z + cvv[k].w * hp4[k].w;
        }
        for (int off = 32; off > 0; off >>= 1) s += __shfl_xor(s, off);

        int c = c0 + i;
        if (mask[c * B_SIZE + b]) s = -3.0e38f;
        if (lane == 0) scoresT[b * C_SIZE + c] = s;

        // online softmax update — s is wave-uniform, so this branch is uniform.
        if (s <= m) {
            float p = __expf(s - m);
            l += p;
#pragma unroll
            for (int k = 0; k < 4; ++k) {
                acc[k].x += p * cvv[k].x;
                acc[k].y += p * cvv[k].y;
                acc[k].z += p * cvv[k].z;
                acc[k].w += p * cvv[k].w;
            }
        } else {
            float scale = __expf(m - s);   // first real row: exp(-huge)=0 zeroes junk
            l = l * scale + 1.f;
#pragma unroll
            for (int k = 0; k < 4; ++k) {
                acc[k].x = acc[k].x * scale + cvv[k].x;
                acc[k].y = acc[k].y * scale + cvv[k].y;
                acc[k].z = acc[k].z * scale + cvv[k].z;
                acc[k].w = acc[k].w * scale + cvv[k].w;
            }
            m = s;
        }
    }

    // ---- combine the 4 waves' partials within the block
    __shared__ float sm[4], sl[4];
    __shared__ float accs[4][D_DIM];   // 16 KiB
    if (lane == 0) { sm[wave] = m; sl[wave] = l; }
    __syncthreads();

    float mb = fmaxf(fmaxf(sm[0], sm[1]), fmaxf(sm[2], sm[3]));
    float myscale = __expf(m - mb);
#pragma unroll
    for (int k = 0; k < 4; ++k) {
        float4 v = acc[k];
        v.x *= myscale; v.y *= myscale; v.z *= myscale; v.w *= myscale;
        *(float4*)&accs[wave][k * 256 + 4 * lane] = v;
    }
    float lb = 0.f;
#pragma unroll
    for (int w = 0; w < 4; ++w) lb += sl[w] * __expf(sm[w] - mb);
    __syncthreads();

    int t = threadIdx.x;   // 0..255, owns d = 4t..4t+3
    float4 r = make_float4(0.f, 0.f, 0.f, 0.f);
#pragma unroll
    for (int w = 0; w < 4; ++w) {
        float4 v = *(const float4*)&accs[w][t * 4];
        r.x += v.x; r.y += v.y; r.z += v.z; r.w += v.w;
    }
    *(float4*)(pacc + ((size_t)g * B_SIZE + b) * D_DIM + t * 4) = r;
    if (t == 0) { pm[g * B_SIZE + b] = mb; pl[g * B_SIZE + b] = lb; }
}

// ---------------- Kernel 3: reduce group partials -> ctx[b][d] in ws (+ M/L)
// grid = (B_SIZE, 4), block = 64 (1 wave). Block handles 256 d's.
__global__ __launch_bounds__(64) void ctx_kernel(const float* __restrict__ pm,
                                                 const float* __restrict__ pl,
                                                 const float* __restrict__ pacc,
                                                 float* __restrict__ Mb,
                                                 float* __restrict__ Lb,
                                                 float* __restrict__ ctxws) {
    int b     = blockIdx.x;
    int dbase = blockIdx.y * 256;
    int lane  = threadIdx.x;   // 0..63

    float mg = (lane < G_NUM) ? pm[lane * B_SIZE + b] : -3.0e38f;
    float M = mg;
    for (int off = 32; off > 0; off >>= 1) M = fmaxf(M, __shfl_xor(M, off));
    float lg = (lane < G_NUM) ? pl[lane * B_SIZE + b] * __expf(mg - M) : 0.f;
    float L = lg;
    for (int off = 32; off > 0; off >>= 1) L += __shfl_xor(L, off);

    __shared__ float ssc[G_NUM];
    if (lane < G_NUM) ssc[lane] = __expf(mg - M);
    __syncthreads();

    float4 r = make_float4(0.f, 0.f, 0.f, 0.f);
#pragma unroll 8
    for (int gi = 0; gi < G_NUM; ++gi) {
        float sc = ssc[gi];
        float4 v = *(const float4*)(pacc + ((size_t)gi * B_SIZE + b) * D_DIM + dbase + 4 * lane);
        r.x += sc * v.x; r.y += sc * v.y; r.z += sc * v.z; r.w += sc * v.w;
    }
    float invL = 1.f / L;
    r.x *= invL; r.y *= invL; r.z *= invL; r.w *= invL;
    *(float4*)(ctxws + b * D_DIM + dbase + 4 * lane) = r;

    if (blockIdx.y == 0 && lane == 0) { Mb[b] = M; Lb[b] = L; }
}

// ---------------- Kernel 4: per (s,b): broadcast ctx row + attn row
// grid = S_LEN*B_SIZE = 2048, block = 256
__global__ __launch_bounds__(256) void out_kernel(const float* __restrict__ ctxws,
                                                  const float* __restrict__ scoresT,
                                                  const float* __restrict__ Mb,
                                                  const float* __restrict__ Lb,
                                                  float* __restrict__ out_ctx,
                                                  float* __restrict__ out_attn) {
    int blk = blockIdx.x;          // s*B + b
    int b   = blk & (B_SIZE - 1);
    int t   = threadIdx.x;

    // context row (broadcast)
    float4 cx = *(const float4*)(ctxws + b * D_DIM + t * 4);
    *(float4*)(out_ctx + (size_t)blk * D_DIM + t * 4) = cx;

    // attention row
    float M    = Mb[b];
    float invL = 1.f / Lb[b];
    const float* srow = scoresT + b * C_SIZE;
    float4* orow = (float4*)(out_attn + (size_t)blk * C_SIZE);
#pragma unroll
    for (int k = 0; k < 2; ++k) {
        int c4 = t + k * 256;
        float4 sv = *(const float4*)(srow + c4 * 4);
        float4 av;
        av.x = __expf(sv.x - M) * invL;
        av.y = __expf(sv.y - M) * invL;
        av.z = __expf(sv.z - M) * invL;
        av.w = __expf(sv.w - M) * invL;
        orow[c4] = av;
    }
}

extern "C" void kernel_launch(void* const* d_in, const int* in_sizes, int n_in,
                              void* d_out, int out_size, void* d_ws, size_t ws_size,
                              hipStream_t stream) {
    // inputs: 0=seqlen(int,unused; S_LEN=64 static), 1=hidden[1,B,H] f32,
    //         2=contextvects[C,B,D] f32, 3=W[D,H] f32, 4=padding_mask[C,B] bool
    const float*         hidden = (const float*)d_in[1];
    const float*         cv     = (const float*)d_in[2];
    const float*         W      = (const float*)d_in[3];
    const unsigned char* mask   = (const unsigned char*)d_in[4];

    float* ws = (float*)d_ws;
    float* hp      = ws;                 // 32768
    float* scoresT = ws + 32768;         // 65536
    float* pm      = ws + 98304;         // 1024
    float* pl      = ws + 99328;         // 1024
    float* Mb      = ws + 100352;        // 32
    float* Lb      = ws + 100384;        // 32
    float* ctxws   = ws + 100416;        // 32768 (16B-aligned)
    float* pacc    = ws + 133184;        // G*B*D = 1048576 (16B-aligned)

    float* out_ctx  = (float*)d_out;                                  // [S,B,D]
    float* out_attn = (float*)d_out + (size_t)S_LEN * B_SIZE * D_DIM; // [S,B,C]

    hp_kernel<<<dim3(B_SIZE, 32), 256, 0, stream>>>(hidden, W, hp);
    fused_kernel<<<dim3(G_NUM, B_SIZE), 256, 0, stream>>>(cv, hp, mask, scoresT, pm, pl, pacc);
    ctx_kernel<<<dim3(B_SIZE, 4), 64, 0, stream>>>(pm, pl, pacc, Mb, Lb, ctxws);
    out_kernel<<<dim3(S_LEN * B_SIZE), 256, 0, stream>>>(ctxws, scoresT, Mb, Lb, out_ctx, out_attn);
}